// Round 1
// baseline (978.293 us; speedup 1.0000x reference)
//
#include <hip/hip_runtime.h>
#include <stdint.h>

#define B_  2
#define NF_ 2048
#define NE_ 4096
#define FD_ 128
#define HD_ 64
#define H_  4

typedef unsigned long long u64;

__device__ __forceinline__ float wave_max64(float v) {
  #pragma unroll
  for (int m = 32; m >= 1; m >>= 1) v = fmaxf(v, __shfl_xor(v, m, 64));
  return v;
}
__device__ __forceinline__ float wave_sum64(float v) {
  #pragma unroll
  for (int m = 32; m >= 1; m >>= 1) v += __shfl_xor(v, m, 64);
  return v;
}

// X1[b,h,n,:] = X0[b,n,:] @ W[h];  dot1 = X1 . a1[h];  dot2 = X1 . a2[h]
__global__ __launch_bounds__(256) void proj_kernel(
    const float* __restrict__ X0, const float* __restrict__ W,
    const float* __restrict__ a1, const float* __restrict__ a2,
    float* __restrict__ X1, float* __restrict__ dot1, float* __restrict__ dot2,
    int N)
{
  const int lane = threadIdx.x & 63;
  const int wid  = threadIdx.x >> 6;
  const long idx = (long)blockIdx.x * 4 + wid;
  if (idx >= (long)B_ * H_ * N) return;
  const int n = (int)(idx % N);
  const int h = (int)((idx / N) % H_);
  const int b = (int)(idx / ((long)N * H_));
  const float* x0 = X0 + ((long)b * N + n) * FD_;
  const float* w  = W + (long)h * FD_ * HD_;
  float acc = 0.f;
  #pragma unroll 8
  for (int f = 0; f < FD_; ++f)
    acc = fmaf(x0[f], w[f * HD_ + lane], acc);
  X1[idx * HD_ + lane] = acc;
  float d1 = wave_sum64(acc * a1[h * HD_ + lane]);
  float d2 = wave_sum64(acc * a2[h * HD_ + lane]);
  if (lane == 0) { dot1[idx] = d1; dot2[idx] = d2; }
}

// pack adj row-major [N][M] int32 -> bits [N][M/64] u64 (bit m%64 = adj!=0)
__global__ __launch_bounds__(256) void bitpack_kernel(
    const int* __restrict__ adj, u64* __restrict__ bits, int N, int M)
{
  const int lane = threadIdx.x & 63;
  const int wid  = threadIdx.x >> 6;
  const long word = (long)blockIdx.x * 4 + wid;
  const int MT = M >> 6;
  if (word >= (long)N * MT) return;
  const long n  = word / MT;
  const int  mt = (int)(word % MT);
  int v = adj[n * (long)M + (long)mt * 64 + lane];
  u64 mask = __ballot(v != 0);
  if (lane == 0) bits[word] = mask;
}

// masked-softmax attention, online softmax over m-tiles of 64.
// Hdst: [B][H][M][64], es: [B][H][N], ed: [B][H][M], bits: [N][M/64]
// out[b][n][h*64+d]  (raw for fe; relu for ef)
template<int RELU>
__global__ __launch_bounds__(256) void attn_kernel(
    const float* __restrict__ Hdst, const float* __restrict__ es,
    const float* __restrict__ ed, const u64* __restrict__ bits,
    float* __restrict__ out, int N, int M)
{
  __shared__ float Et[64 * 64];       // [m][d] tile, 16KB
  __shared__ float edt[64];
  __shared__ float wl[4][16 * 64];    // per-wave weight scratch, 16KB

  const int lane = threadIdx.x & 63;
  const int wid  = threadIdx.x >> 6;
  const int ntiles = N >> 6;
  const int nt = blockIdx.x % ntiles;
  const int h  = (blockIdx.x / ntiles) % H_;
  const int b  = blockIdx.x / (ntiles * H_);
  const int n0 = nt * 64 + wid * 16;
  const float* esp = es + ((long)b * H_ + h) * N;
  const float* edp = ed + ((long)b * H_ + h) * M;
  const float* Hp  = Hdst + ((long)b * H_ + h) * (long)M * HD_;
  const int MT = M >> 6;

  float es_r[16], acc[16], mrun[16], lrun[16];
  #pragma unroll
  for (int r = 0; r < 16; ++r) {
    es_r[r] = esp[n0 + r];
    acc[r] = 0.f; mrun[r] = -1e30f; lrun[r] = 0.f;
  }

  for (int mt = 0; mt < MT; ++mt) {
    __syncthreads();  // prior tile's reads complete
    const float4* src = (const float4*)(Hp + (long)mt * 64 * HD_);
    float4* dst = (float4*)Et;
    #pragma unroll
    for (int k = 0; k < 4; ++k)
      dst[threadIdx.x + 256 * k] = src[threadIdx.x + 256 * k];
    if (threadIdx.x < 64) edt[threadIdx.x] = edp[mt * 64 + threadIdx.x];
    __syncthreads();
    const float edv = edt[lane];

    // ---- weight phase: lane = m within tile ----
    #pragma unroll
    for (int r = 0; r < 16; ++r) {
      float s = es_r[r] + edv;
      s = s > 0.f ? s : 0.2f * s;                  // leaky_relu(0.2)
      u64 mask = bits[(long)(n0 + r) * MT + mt];
      if (!((mask >> lane) & 1ull)) s = -1e9f;     // mask AFTER lrelu
      float tmax = wave_max64(s);
      float mnew = fmaxf(mrun[r], tmax);
      float scale = __expf(mrun[r] - mnew);
      float wv = __expf(s - mnew);
      lrun[r] = lrun[r] * scale + wave_sum64(wv);
      mrun[r] = mnew;
      acc[r] *= scale;
      wl[wid][r * 64 + lane] = wv;
    }
    // ---- FMA phase: lane = d; wave-local LDS (in-order per wave) ----
    #pragma unroll 8
    for (int i = 0; i < 64; ++i) {
      float ev = Et[i * 64 + lane];
      #pragma unroll
      for (int r = 0; r < 16; ++r)
        acc[r] = fmaf(wl[wid][r * 64 + i], ev, acc[r]);
    }
  }

  #pragma unroll
  for (int r = 0; r < 16; ++r) {
    float v = acc[r] / lrun[r];
    if (RELU) v = fmaxf(v, 0.f);
    out[((long)b * N + n0 + r) * 256 + h * HD_ + lane] = v;
  }
}

// in-place softmax over the 256-channel axis (one row per block)
__global__ __launch_bounds__(256) void softmax256_kernel(float* __restrict__ io)
{
  const int t = threadIdx.x;
  const int lane = t & 63, wid = t >> 6;
  float v = io[(long)blockIdx.x * 256 + t];
  __shared__ float red[8];
  float m = wave_max64(v);
  if (lane == 0) red[wid] = m;
  __syncthreads();
  m = fmaxf(fmaxf(red[0], red[1]), fmaxf(red[2], red[3]));
  float e = __expf(v - m);
  float s = wave_sum64(e);
  if (lane == 0) red[4 + wid] = s;
  __syncthreads();
  s = (red[4] + red[5]) + (red[6] + red[7]);
  io[(long)blockIdx.x * 256 + t] = e / s;
}

extern "C" void kernel_launch(void* const* d_in, const int* in_sizes, int n_in,
                              void* d_out, int out_size, void* d_ws, size_t ws_size,
                              hipStream_t stream)
{
  const float* F0   = (const float*)d_in[0];
  const float* E0   = (const float*)d_in[1];
  const int* adj_fe = (const int*)d_in[2];
  const int* adj_ef = (const int*)d_in[3];
  const float* Wf   = (const float*)d_in[4];
  const float* We   = (const float*)d_in[5];
  const float* a_fe = (const float*)d_in[6];
  const float* a_ef = (const float*)d_in[7];
  float* out = (float*)d_out;

  float* ws = (float*)d_ws;
  float* F1    = ws;                                  // B*H*NF*64 = 1048576 f
  float* E1    = F1 + (size_t)B_ * H_ * NF_ * HD_;    // B*H*NE*64 = 2097152 f
  float* es_fe = E1 + (size_t)B_ * H_ * NE_ * HD_;    // B*H*NF
  float* ed_ef = es_fe + (size_t)B_ * H_ * NF_;       // B*H*NF
  float* ed_fe = ed_ef + (size_t)B_ * H_ * NF_;       // B*H*NE
  float* es_ef = ed_fe + (size_t)B_ * H_ * NE_;       // B*H*NE
  u64* bits_fe = (u64*)(es_ef + (size_t)B_ * H_ * NE_);      // NF*(NE/64)
  u64* bits_ef = bits_fe + (size_t)NF_ * (NE_ / 64);         // NE*(NF/64)

  // projections + attention-logit dot products
  proj_kernel<<<B_ * H_ * NF_ / 4, 256, 0, stream>>>(F0, Wf, a_fe, a_ef,
                                                     F1, es_fe, ed_ef, NF_);
  proj_kernel<<<B_ * H_ * NE_ / 4, 256, 0, stream>>>(E0, We, a_fe, a_ef,
                                                     E1, ed_fe, es_ef, NE_);
  // adjacency bit-packing
  bitpack_kernel<<<(NF_ * (NE_ / 64)) / 4, 256, 0, stream>>>(adj_fe, bits_fe, NF_, NE_);
  bitpack_kernel<<<(NE_ * (NF_ / 64)) / 4, 256, 0, stream>>>(adj_ef, bits_ef, NE_, NF_);
  // attentions
  attn_kernel<0><<<B_ * H_ * (NF_ / 64), 256, 0, stream>>>(
      E1, es_fe, ed_fe, bits_fe, out, NF_, NE_);
  attn_kernel<1><<<B_ * H_ * (NE_ / 64), 256, 0, stream>>>(
      F1, es_ef, ed_ef, bits_ef, out + (size_t)B_ * NF_ * 256, NE_, NF_);
  // cross-head softmax on out_fe (in place)
  softmax256_kernel<<<B_ * NF_, 256, 0, stream>>>(out);
}

// Round 2
// 362.752 us; speedup vs baseline: 2.6969x; 2.6969x over previous
//
#include <hip/hip_runtime.h>
#include <hip/hip_bf16.h>
#include <stdint.h>

#define B_  2
#define NF_ 2048
#define NE_ 4096
#define FD_ 128
#define HD_ 64
#define H_  4

typedef unsigned long long u64;
typedef __attribute__((ext_vector_type(4))) float f32x4;
typedef __attribute__((ext_vector_type(8))) short bf16x8;

__device__ __forceinline__ float wave_max64(float v) {
  #pragma unroll
  for (int m = 32; m >= 1; m >>= 1) v = fmaxf(v, __shfl_xor(v, m, 64));
  return v;
}
__device__ __forceinline__ float wave_sum64(float v) {
  #pragma unroll
  for (int m = 32; m >= 1; m >>= 1) v += __shfl_xor(v, m, 64);
  return v;
}

// X1[b,h,n,:] = X0[b,n,:] @ W[h];  dot1 = X1 . a1[h];  dot2 = X1 . a2[h]
__global__ __launch_bounds__(256) void proj_kernel(
    const float* __restrict__ X0, const float* __restrict__ W,
    const float* __restrict__ a1, const float* __restrict__ a2,
    float* __restrict__ X1, float* __restrict__ dot1, float* __restrict__ dot2,
    int N)
{
  const int lane = threadIdx.x & 63;
  const int wid  = threadIdx.x >> 6;
  const long idx = (long)blockIdx.x * 4 + wid;
  if (idx >= (long)B_ * H_ * N) return;
  const int n = (int)(idx % N);
  const int h = (int)((idx / N) % H_);
  const int b = (int)(idx / ((long)N * H_));
  const float* x0 = X0 + ((long)b * N + n) * FD_;
  const float* w  = W + (long)h * FD_ * HD_;
  float acc = 0.f;
  #pragma unroll 8
  for (int f = 0; f < FD_; ++f)
    acc = fmaf(x0[f], w[f * HD_ + lane], acc);
  X1[idx * HD_ + lane] = acc;
  float d1 = wave_sum64(acc * a1[h * HD_ + lane]);
  float d2 = wave_sum64(acc * a2[h * HD_ + lane]);
  if (lane == 0) { dot1[idx] = d1; dot2[idx] = d2; }
}

// transpose+convert: X1 f32 [bh][N][64]  ->  Xt bf16 [bh][64][N]
__global__ __launch_bounds__(256) void t64_kernel(
    const float* __restrict__ X1, __hip_bfloat16* __restrict__ Xt, int N)
{
  const size_t tid = (size_t)blockIdx.x * 256 + threadIdx.x;
  const int d = (int)(tid & 63);
  const size_t rest = tid >> 6;
  const int NC = N >> 3;
  const int nc = (int)(rest % NC);
  const int bh = (int)(rest / NC);
  const float* src = X1 + ((size_t)bh * N + (size_t)nc * 8) * HD_ + d;
  unsigned short u[8];
  #pragma unroll
  for (int j = 0; j < 8; ++j) {
    unsigned x = __float_as_uint(src[(size_t)j * HD_]);
    u[j] = (unsigned short)((x + 0x7FFFu + ((x >> 16) & 1u)) >> 16);  // RNE
  }
  uint4 w;
  w.x = u[0] | ((unsigned)u[1] << 16);
  w.y = u[2] | ((unsigned)u[3] << 16);
  w.z = u[4] | ((unsigned)u[5] << 16);
  w.w = u[6] | ((unsigned)u[7] << 16);
  *(uint4*)(Xt + ((size_t)bh * HD_ + d) * N + (size_t)nc * 8) = w;
}

// pack adj row-major [N][M] int32 -> bits [N][M/64] u64 (bit m%64 = adj!=0)
__global__ __launch_bounds__(256) void bitpack_kernel(
    const int* __restrict__ adj, u64* __restrict__ bits, int N, int M)
{
  const int lane = threadIdx.x & 63;
  const int wid  = threadIdx.x >> 6;
  const long word = (long)blockIdx.x * 4 + wid;
  const int MT = M >> 6;
  if (word >= (long)N * MT) return;
  const long n  = word / MT;
  const int  mt = (int)(word % MT);
  int v = adj[n * (long)M + (long)mt * 64 + lane];
  u64 mask = __ballot(v != 0);
  if (lane == 0) bits[word] = mask;
}

// MFMA masked-softmax attention (fixed-max C=12, denominator via ones-MFMA).
// Vt: [bh][64][M] bf16 (d-major), es: [bh][N], ed: [bh][M], bits: [N][M/64]
// out[b][n][h*64+d]  (raw for fe; relu for ef)
template<int RELU>
__global__ __launch_bounds__(256) void attn_mfma_kernel(
    const __hip_bfloat16* __restrict__ Vt, const float* __restrict__ es,
    const float* __restrict__ ed, const u64* __restrict__ bits,
    float* __restrict__ out, int N, int M)
{
  // pool: VBUF0 [0,8K), VBUF1 [8K,16K), P [16K + wid*2K, ...24K)
  // epilogue aliases: Ot per wave at wid*4352 (16x68 f32)
  __shared__ __align__(16) char pool[24576];
  const int t = threadIdx.x, lane = t & 63, wid = t >> 6;
  const int ntiles = N >> 6;
  const int nt = blockIdx.x % ntiles;
  const int h  = (blockIdx.x / ntiles) % H_;
  const int b  = blockIdx.x / (ntiles * H_);
  const int bh = b * H_ + h;
  const int n0 = nt * 64, nw = n0 + wid * 16;
  const int MT = M >> 6;
  const float* esp = es + (size_t)bh * N;
  const float* edp = ed + (size_t)bh * M;
  const __hip_bfloat16* vp = Vt + (size_t)bh * HD_ * M;

  float es_r[16];
  #pragma unroll
  for (int r = 0; r < 16; ++r) es_r[r] = esp[nw + r];

  f32x4 accT[4] = {{0.f,0.f,0.f,0.f},{0.f,0.f,0.f,0.f},
                   {0.f,0.f,0.f,0.f},{0.f,0.f,0.f,0.f}};
  f32x4 accS = {0.f,0.f,0.f,0.f};
  bf16x8 ones;
  #pragma unroll
  for (int i = 0; i < 8; ++i) ones[i] = (short)0x3F80;  // bf16 1.0

  // staging: thread covers V row d = t>>2, 32B chunk (t&3); XOR-swizzled LDS
  const int sd = t >> 2, sc = t & 3;
  const __hip_bfloat16* gsrc = vp + (size_t)sd * M + sc * 16;
  const int sb0 = sd * 128 + (((sc * 32) + 0)  ^ ((sd & 7) << 4));
  const int sb1 = sd * 128 + (((sc * 32) + 16) ^ ((sd & 7) << 4));
  char* const pb = pool + 16384 + wid * 2048;

  uint4 g0 = *(const uint4*)(gsrc);
  uint4 g1 = *(const uint4*)(gsrc + 8);

  const int rA   = lane & 15;          // fragment row (d-local / n-local)
  const int kb   = (lane >> 4) * 16;   // 16B sub-block by lane quad
  const int swzR = (rA & 7) << 4;

  for (int mt = 0; mt < MT; ++mt) {
    char* vb = pool + (mt & 1) * 8192;
    *(uint4*)(vb + sb0) = g0;
    *(uint4*)(vb + sb1) = g1;
    __syncthreads();
    if (mt + 1 < MT) {                      // prefetch next tile (overlaps compute)
      const __hip_bfloat16* gn = gsrc + (mt + 1) * 64;
      g0 = *(const uint4*)(gn);
      g1 = *(const uint4*)(gn + 8);
    }
    // ---- weight phase: lane = m within tile ----
    const float edv = edp[mt * 64 + lane];
    #pragma unroll
    for (int r = 0; r < 16; ++r) {
      float s = es_r[r] + edv;
      s = fmaxf(s, 0.2f * s);               // leaky_relu(0.2)
      float e = __expf(s - 12.0f);          // fixed max; no overflow (|s|<~15)
      u64 mask = bits[(size_t)(nw + r) * MT + mt];
      unsigned mw = (unsigned)(lane < 32 ? mask : (mask >> 32));
      e = ((mw >> (lane & 31)) & 1u) ? e : 0.0f;
      *(__hip_bfloat16*)(pb + r * 128 + ((lane * 2) ^ ((r & 7) << 4))) =
          __float2bfloat16(e);
    }
    // ---- MFMA phase: O^T += V^T * P^T  (wave-local P, no barrier needed) ----
    #pragma unroll
    for (int ks = 0; ks < 2; ++ks) {
      bf16x8 bfrag = *(const bf16x8*)(pb + rA * 128 + ((ks * 64 + kb) ^ swzR));
      accS = __builtin_amdgcn_mfma_f32_16x16x32_bf16(ones, bfrag, accS, 0, 0, 0);
      #pragma unroll
      for (int dblk = 0; dblk < 4; ++dblk) {
        bf16x8 afrag = *(const bf16x8*)(vb + (dblk * 16 + rA) * 128 +
                                        ((ks * 64 + kb) ^ swzR));
        accT[dblk] = __builtin_amdgcn_mfma_f32_16x16x32_bf16(afrag, bfrag,
                                                             accT[dblk], 0, 0, 0);
      }
    }
  }

  __syncthreads();   // all waves done with V/P before aliasing pool
  // epilogue: lane holds O^T[d=dblk*16+(l>>4)*4+reg][n=l&15]; lrun = accS[0]
  const float inv = 1.0f / accS[0];
  float* ot = (float*)(pool + wid * 4352);   // [16 n][68 d] padded
  #pragma unroll
  for (int dblk = 0; dblk < 4; ++dblk) {
    #pragma unroll
    for (int reg = 0; reg < 4; ++reg) {
      float v = accT[dblk][reg] * inv;
      if (RELU) v = fmaxf(v, 0.0f);
      ot[rA * 68 + dblk * 16 + (lane >> 4) * 4 + reg] = v;
    }
  }
  #pragma unroll
  for (int j = 0; j < 4; ++j) {             // wave-local readback, coalesced store
    int nl = j * 4 + (lane >> 4);
    f32x4 o = *(const f32x4*)(ot + nl * 68 + rA * 4);
    *(f32x4*)(out + ((size_t)(b * N + n0 + wid * 16 + nl)) * 256 + h * HD_ + rA * 4) = o;
  }
}

// in-place softmax over the 256-channel axis (one row per block)
__global__ __launch_bounds__(256) void softmax256_kernel(float* __restrict__ io)
{
  const int t = threadIdx.x;
  const int lane = t & 63, wid = t >> 6;
  float v = io[(long)blockIdx.x * 256 + t];
  __shared__ float red[8];
  float m = wave_max64(v);
  if (lane == 0) red[wid] = m;
  __syncthreads();
  m = fmaxf(fmaxf(red[0], red[1]), fmaxf(red[2], red[3]));
  float e = __expf(v - m);
  float s = wave_sum64(e);
  if (lane == 0) red[4 + wid] = s;
  __syncthreads();
  s = (red[4] + red[5]) + (red[6] + red[7]);
  io[(long)blockIdx.x * 256 + t] = e / s;
}

extern "C" void kernel_launch(void* const* d_in, const int* in_sizes, int n_in,
                              void* d_out, int out_size, void* d_ws, size_t ws_size,
                              hipStream_t stream)
{
  const float* F0   = (const float*)d_in[0];
  const float* E0   = (const float*)d_in[1];
  const int* adj_fe = (const int*)d_in[2];
  const int* adj_ef = (const int*)d_in[3];
  const float* Wf   = (const float*)d_in[4];
  const float* We   = (const float*)d_in[5];
  const float* a_fe = (const float*)d_in[6];
  const float* a_ef = (const float*)d_in[7];
  float* out = (float*)d_out;

  float* ws = (float*)d_ws;
  float* F1    = ws;                                  // B*H*NF*64 = 1048576 f
  float* E1    = F1 + (size_t)B_ * H_ * NF_ * HD_;    // B*H*NE*64 = 2097152 f
  float* es_fe = E1 + (size_t)B_ * H_ * NE_ * HD_;    // B*H*NF
  float* ed_ef = es_fe + (size_t)B_ * H_ * NF_;       // B*H*NF
  float* ed_fe = ed_ef + (size_t)B_ * H_ * NF_;       // B*H*NE
  float* es_ef = ed_fe + (size_t)B_ * H_ * NE_;       // B*H*NE
  u64* bits_fe = (u64*)(es_ef + (size_t)B_ * H_ * NE_);      // NF*(NE/64)
  u64* bits_ef = bits_fe + (size_t)NF_ * (NE_ / 64);         // NE*(NF/64)
  __hip_bfloat16* Ft = (__hip_bfloat16*)(bits_ef + (size_t)NE_ * (NF_ / 64)); // B*H*64*NF
  __hip_bfloat16* Et = Ft + (size_t)B_ * H_ * HD_ * NF_;                      // B*H*64*NE

  // projections + attention-logit dot products
  proj_kernel<<<B_ * H_ * NF_ / 4, 256, 0, stream>>>(F0, Wf, a_fe, a_ef,
                                                     F1, es_fe, ed_ef, NF_);
  proj_kernel<<<B_ * H_ * NE_ / 4, 256, 0, stream>>>(E0, We, a_fe, a_ef,
                                                     E1, ed_fe, es_ef, NE_);
  // bf16 transposed copies of the projected features (V operands, d-major)
  t64_kernel<<<(B_ * H_ * HD_ * (NF_ / 8)) / 256, 256, 0, stream>>>(F1, Ft, NF_);
  t64_kernel<<<(B_ * H_ * HD_ * (NE_ / 8)) / 256, 256, 0, stream>>>(E1, Et, NE_);
  // adjacency bit-packing
  bitpack_kernel<<<(NF_ * (NE_ / 64)) / 4, 256, 0, stream>>>(adj_fe, bits_fe, NF_, NE_);
  bitpack_kernel<<<(NE_ * (NF_ / 64)) / 4, 256, 0, stream>>>(adj_ef, bits_ef, NE_, NF_);
  // attentions
  attn_mfma_kernel<0><<<B_ * H_ * (NF_ / 64), 256, 0, stream>>>(
      Et, es_fe, ed_fe, bits_fe, out, NF_, NE_);
  attn_mfma_kernel<1><<<B_ * H_ * (NE_ / 64), 256, 0, stream>>>(
      Ft, es_ef, ed_ef, bits_ef, out + (size_t)B_ * NF_ * 256, NE_, NF_);
  // cross-head softmax on out_fe (in place)
  softmax256_kernel<<<B_ * NF_, 256, 0, stream>>>(out);
}

// Round 3
// 241.240 us; speedup vs baseline: 4.0553x; 1.5037x over previous
//
#include <hip/hip_runtime.h>
#include <hip/hip_bf16.h>
#include <stdint.h>

#define B_  2
#define NF_ 2048
#define NE_ 4096
#define FD_ 128
#define HD_ 64
#define H_  4

typedef unsigned long long u64;
typedef __attribute__((ext_vector_type(4))) float f32x4;
typedef __attribute__((ext_vector_type(8))) short bf16x8;

__device__ __forceinline__ float wave_sum64(float v) {
  #pragma unroll
  for (int m = 32; m >= 1; m >>= 1) v += __shfl_xor(v, m, 64);
  return v;
}
__device__ __forceinline__ float wave_max64(float v) {
  #pragma unroll
  for (int m = 32; m >= 1; m >>= 1) v = fmaxf(v, __shfl_xor(v, m, 64));
  return v;
}

// proj: 8 rows/wave. Writes transposed bf16 Vt[bh][d][n] + both logit dots.
__global__ __launch_bounds__(256) void proj_kernel(
    const float* __restrict__ X0, const float* __restrict__ W,
    const float* __restrict__ a1, const float* __restrict__ a2,
    __hip_bfloat16* __restrict__ Vt, float* __restrict__ dot1,
    float* __restrict__ dot2, int N)
{
  const int lane = threadIdx.x & 63;
  const int wid  = threadIdx.x >> 6;
  const int job  = blockIdx.x * 4 + wid;    // 8 rows each
  const int nj = N >> 3;
  const int n8 = job % nj;
  const int h  = (job / nj) % H_;
  const int b  = job / (nj * H_);
  const int bh = b * H_ + h;
  const float* x0 = X0 + ((size_t)b * N + (size_t)n8 * 8) * FD_;
  const float* w  = W + (size_t)h * FD_ * HD_;
  float acc[8] = {0,0,0,0,0,0,0,0};
  #pragma unroll 4
  for (int f = 0; f < FD_; ++f) {
    float wv = w[f * HD_ + lane];
    #pragma unroll
    for (int r = 0; r < 8; ++r)
      acc[r] = fmaf(x0[r * FD_ + f], wv, acc[r]);
  }
  unsigned short u[8];
  #pragma unroll
  for (int r = 0; r < 8; ++r) {
    unsigned x = __float_as_uint(acc[r]);
    u[r] = (unsigned short)((x + 0x7FFFu + ((x >> 16) & 1u)) >> 16);  // RNE
  }
  uint4 pk;
  pk.x = u[0] | ((unsigned)u[1] << 16);
  pk.y = u[2] | ((unsigned)u[3] << 16);
  pk.z = u[4] | ((unsigned)u[5] << 16);
  pk.w = u[6] | ((unsigned)u[7] << 16);
  *(uint4*)(Vt + ((size_t)bh * HD_ + lane) * N + (size_t)n8 * 8) = pk;
  const float a1v = a1[h * HD_ + lane], a2v = a2[h * HD_ + lane];
  #pragma unroll
  for (int r = 0; r < 8; ++r) {
    float d1 = wave_sum64(acc[r] * a1v);
    float d2 = wave_sum64(acc[r] * a2v);
    if (lane == 0) {
      dot1[(size_t)bh * N + n8 * 8 + r] = d1;
      dot2[(size_t)bh * N + n8 * 8 + r] = d2;
    }
  }
}

// pack adj row-major [N][M] int32 -> bits [N][M/64] u64
__global__ __launch_bounds__(256) void bitpack_kernel(
    const int* __restrict__ adj, u64* __restrict__ bits, int N, int M)
{
  const int lane = threadIdx.x & 63;
  const int wid  = threadIdx.x >> 6;
  const long word = (long)blockIdx.x * 4 + wid;
  const int MT = M >> 6;
  if (word >= (long)N * MT) return;
  const long n  = word / MT;
  const int  mt = (int)(word % MT);
  int v = adj[n * (long)M + (long)mt * 64 + lane];
  u64 mask = __ballot(v != 0);
  if (lane == 0) bits[word] = mask;
}

__global__ __launch_bounds__(256) void zero_kernel(f32x4* __restrict__ p, int n)
{
  for (int i = blockIdx.x * 256 + threadIdx.x; i < n; i += gridDim.x * 256)
    p[i] = (f32x4){0.f, 0.f, 0.f, 0.f};
}

// attention partials: one wave = 32 rows x (TPJ*64) cols slice. P kept in
// registers as the MFMA A-fragment (no LDS, no barriers). Denominator via
// ones-B MFMA. Partials accumulated with f32 atomics (fixed-max softmax
// makes partials additive).
template<int TPJ>
__global__ __launch_bounds__(256, 3) void attn_part_kernel(
    const __hip_bfloat16* __restrict__ Vt, const float* __restrict__ es,
    const float* __restrict__ ed, const u64* __restrict__ bits,
    float* __restrict__ Opart, float* __restrict__ Spart,
    int N, int M, int msplit)
{
  const int lane = threadIdx.x & 63;
  const int wid  = threadIdx.x >> 6;
  const int gid  = blockIdx.x * 4 + wid;
  const int nch  = N >> 5;
  const int sp = gid % msplit;
  const int nc = (gid / msplit) % nch;
  const int bh = gid / (msplit * nch);
  const int n0 = nc * 32;
  const int MT = M >> 6;
  const int mt0 = sp * TPJ;
  const int cl = lane & 15, kq = lane >> 4;

  const float* esp = es + (size_t)bh * N;
  const float* edp = ed + (size_t)bh * M;
  const __hip_bfloat16* vp = Vt + (size_t)bh * HD_ * M;
  const u64* bp0 = bits + (size_t)(n0 + cl) * MT;
  const u64* bp1 = bits + (size_t)(n0 + 16 + cl) * MT;
  const float es0 = esp[n0 + cl], es1 = esp[n0 + 16 + cl];

  f32x4 accT[2][4] = {};
  f32x4 accS[2] = {};
  bf16x8 ones;
  #pragma unroll
  for (int i = 0; i < 8; ++i) ones[i] = (short)0x3F80;  // bf16 1.0

  for (int t = 0; t < TPJ; ++t) {
    const int mt = mt0 + t;
    // V B-fragments straight from L2: vf[ks][db]
    bf16x8 vf[2][4];
    #pragma unroll
    for (int ks = 0; ks < 2; ++ks)
      #pragma unroll
      for (int db = 0; db < 4; ++db)
        vf[ks][db] = *(const bf16x8*)(vp + (size_t)(db * 16 + cl) * M
                                      + mt * 64 + ks * 32 + kq * 8);
    // ed for this lane's k positions
    const float* e0 = edp + mt * 64 + kq * 8;
    const f32x4 ed0a = *(const f32x4*)(e0);
    const f32x4 ed0b = *(const f32x4*)(e0 + 4);
    const f32x4 ed1a = *(const f32x4*)(e0 + 32);
    const f32x4 ed1b = *(const f32x4*)(e0 + 36);
    const u64 mmr[2] = { bp0[mt], bp1[mt] };
    // P A-fragments in registers
    bf16x8 pf[2][2];
    #pragma unroll
    for (int rf = 0; rf < 2; ++rf) {
      const float esv = rf ? es1 : es0;
      #pragma unroll
      for (int ks = 0; ks < 2; ++ks) {
        unsigned mw = (unsigned)(ks ? (mmr[rf] >> 32) : mmr[rf]);
        mw >>= (kq * 8);
        #pragma unroll
        for (int j = 0; j < 8; ++j) {
          float edv = ks ? (j < 4 ? ed1a[j] : ed1b[j - 4])
                         : (j < 4 ? ed0a[j] : ed0b[j - 4]);
          float s = esv + edv;
          s = fmaxf(s, 0.2f * s);          // leaky_relu(0.2)
          float e = __expf(s - 12.0f);     // fixed max (|s| << 12)
          e = (mw & (1u << j)) ? e : 0.0f; // mask AFTER lrelu
          __hip_bfloat16 hb = __float2bfloat16(e);
          pf[rf][ks][j] = *(short*)&hb;
        }
      }
    }
    #pragma unroll
    for (int ks = 0; ks < 2; ++ks) {
      #pragma unroll
      for (int rf = 0; rf < 2; ++rf)
        accS[rf] = __builtin_amdgcn_mfma_f32_16x16x32_bf16(
            pf[rf][ks], ones, accS[rf], 0, 0, 0);
      #pragma unroll
      for (int db = 0; db < 4; ++db)
        #pragma unroll
        for (int rf = 0; rf < 2; ++rf)
          accT[rf][db] = __builtin_amdgcn_mfma_f32_16x16x32_bf16(
              pf[rf][ks], vf[ks][db], accT[rf][db], 0, 0, 0);
    }
  }
  // epilogue: D layout row=(kq*4+reg) -> n, col=cl -> d
  #pragma unroll
  for (int rf = 0; rf < 2; ++rf) {
    #pragma unroll
    for (int reg = 0; reg < 4; ++reg) {
      const int n = n0 + rf * 16 + kq * 4 + reg;
      #pragma unroll
      for (int db = 0; db < 4; ++db)
        atomicAdd(&Opart[((size_t)bh * N + n) * HD_ + db * 16 + cl],
                  accT[rf][db][reg]);
      if (cl == 0)
        atomicAdd(&Spart[(size_t)bh * N + n], accS[rf][reg]);
    }
  }
}

// fe finalize: divide + fused cross-head softmax. grid = B*NF
__global__ __launch_bounds__(256) void finalize_fe_kernel(
    const float* __restrict__ Opart, const float* __restrict__ Spart,
    float* __restrict__ out)
{
  const int t = threadIdx.x, lane = t & 63, wid = t >> 6;
  const int n = blockIdx.x % NF_, b = blockIdx.x / NF_;
  const int bh = b * H_ + wid;
  float v = Opart[((size_t)bh * NF_ + n) * HD_ + lane]
          / Spart[(size_t)bh * NF_ + n];
  __shared__ float red[8];
  float m = wave_max64(v);
  if (lane == 0) red[wid] = m;
  __syncthreads();
  m = fmaxf(fmaxf(red[0], red[1]), fmaxf(red[2], red[3]));
  float e = __expf(v - m);
  float s = wave_sum64(e);
  if (lane == 0) red[4 + wid] = s;
  __syncthreads();
  s = (red[4] + red[5]) + (red[6] + red[7]);
  out[((size_t)b * NF_ + n) * 256 + t] = e / s;
}

// ef finalize: divide + relu. grid = B*NE
__global__ __launch_bounds__(256) void finalize_ef_kernel(
    const float* __restrict__ Opart, const float* __restrict__ Spart,
    float* __restrict__ out)
{
  const int t = threadIdx.x, lane = t & 63, wid = t >> 6;
  const int n = blockIdx.x % NE_, b = blockIdx.x / NE_;
  const int bh = b * H_ + wid;
  float v = Opart[((size_t)bh * NE_ + n) * HD_ + lane]
          / Spart[(size_t)bh * NE_ + n];
  out[((size_t)b * NE_ + n) * 256 + t] = fmaxf(v, 0.0f);
}

extern "C" void kernel_launch(void* const* d_in, const int* in_sizes, int n_in,
                              void* d_out, int out_size, void* d_ws, size_t ws_size,
                              hipStream_t stream)
{
  const float* F0   = (const float*)d_in[0];
  const float* E0   = (const float*)d_in[1];
  const int* adj_fe = (const int*)d_in[2];
  const int* adj_ef = (const int*)d_in[3];
  const float* Wf   = (const float*)d_in[4];
  const float* We   = (const float*)d_in[5];
  const float* a_fe = (const float*)d_in[6];
  const float* a_ef = (const float*)d_in[7];
  float* out = (float*)d_out;

  float* ws = (float*)d_ws;
  float* es_fe = ws;                               // 8*2048
  float* ed_ef = es_fe + (size_t)B_ * H_ * NF_;    // 8*2048
  float* ed_fe = ed_ef + (size_t)B_ * H_ * NF_;    // 8*4096
  float* es_ef = ed_fe + (size_t)B_ * H_ * NE_;    // 8*4096
  u64* bits_fe = (u64*)(es_ef + (size_t)B_ * H_ * NE_);   // 2048*64 u64
  u64* bits_ef = bits_fe + (size_t)NF_ * (NE_ / 64);      // 4096*32 u64
  __hip_bfloat16* Ft = (__hip_bfloat16*)(bits_ef + (size_t)NE_ * (NF_ / 64));
  __hip_bfloat16* Et = Ft + (size_t)B_ * H_ * HD_ * NF_;
  float* Opart_fe = (float*)(Et + (size_t)B_ * H_ * HD_ * NE_);  // 8*2048*64
  float* Spart_fe = Opart_fe + (size_t)B_ * H_ * NF_ * HD_;      // 8*2048
  float* Opart_ef = Spart_fe + (size_t)B_ * H_ * NF_;            // 8*4096*64
  float* Spart_ef = Opart_ef + (size_t)B_ * H_ * NE_ * HD_;      // 8*4096

  const int zero_f = (int)((size_t)B_ * H_ * (NF_ + NE_) * (HD_ + 1));
  zero_kernel<<<1024, 256, 0, stream>>>((f32x4*)Opart_fe, zero_f / 4);

  proj_kernel<<<B_ * H_ * NF_ / 32, 256, 0, stream>>>(F0, Wf, a_fe, a_ef,
                                                      Ft, es_fe, ed_ef, NF_);
  proj_kernel<<<B_ * H_ * NE_ / 32, 256, 0, stream>>>(E0, We, a_fe, a_ef,
                                                      Et, ed_fe, es_ef, NE_);
  bitpack_kernel<<<(NF_ * (NE_ / 64)) / 4, 256, 0, stream>>>(adj_fe, bits_fe, NF_, NE_);
  bitpack_kernel<<<(NE_ * (NF_ / 64)) / 4, 256, 0, stream>>>(adj_ef, bits_ef, NE_, NF_);

  // fe: N=2048 rows, M=4096 cols, MT=64 tiles, msplit=8 -> TPJ=8, 4096 waves
  attn_part_kernel<8><<<(B_ * H_ * (NF_ / 32) * 8) / 4, 256, 0, stream>>>(
      Et, es_fe, ed_fe, bits_fe, Opart_fe, Spart_fe, NF_, NE_, 8);
  // ef: N=4096 rows, M=2048 cols, MT=32 tiles, msplit=4 -> TPJ=8, 4096 waves
  attn_part_kernel<8><<<(B_ * H_ * (NE_ / 32) * 4) / 4, 256, 0, stream>>>(
      Ft, es_ef, ed_ef, bits_ef, Opart_ef, Spart_ef, NE_, NF_, 4);

  finalize_fe_kernel<<<B_ * NF_, 256, 0, stream>>>(Opart_fe, Spart_fe, out);
  finalize_ef_kernel<<<B_ * NE_, 256, 0, stream>>>(Opart_ef, Spart_ef,
                                                   out + (size_t)B_ * NF_ * 256);
}

// Round 4
// 226.765 us; speedup vs baseline: 4.3141x; 1.0638x over previous
//
#include <hip/hip_runtime.h>
#include <hip/hip_bf16.h>
#include <stdint.h>

#define B_  2
#define NF_ 2048
#define NE_ 4096
#define FD_ 128
#define HD_ 64
#define H_  4

typedef unsigned long long u64;
typedef __attribute__((ext_vector_type(4))) float f32x4;
typedef __attribute__((ext_vector_type(8))) short bf16x8;

__device__ __forceinline__ float wave_sum64(float v) {
  #pragma unroll
  for (int m = 32; m >= 1; m >>= 1) v += __shfl_xor(v, m, 64);
  return v;
}
__device__ __forceinline__ float wave_max64(float v) {
  #pragma unroll
  for (int m = 32; m >= 1; m >>= 1) v = fmaxf(v, __shfl_xor(v, m, 64));
  return v;
}

// ---- proj: 8 rows/wave; writes transposed bf16 Vt[bh][d][n] + logit dots ----
__device__ __forceinline__ void proj_body(
    const float* __restrict__ X0, const float* __restrict__ W,
    const float* __restrict__ a1, const float* __restrict__ a2,
    __hip_bfloat16* __restrict__ Vt, float* __restrict__ dot1,
    float* __restrict__ dot2, int N, int job)
{
  const int lane = threadIdx.x & 63;
  const int nj = N >> 3;
  const int n8 = job % nj;
  const int h  = (job / nj) & (H_ - 1);
  const int b  = job / (nj * H_);
  const int bh = b * H_ + h;
  const float* x0 = X0 + ((size_t)b * N + (size_t)n8 * 8) * FD_;
  const float* w  = W + (size_t)h * FD_ * HD_;
  float acc[8] = {0,0,0,0,0,0,0,0};
  #pragma unroll 4
  for (int f = 0; f < FD_; ++f) {
    float wv = w[f * HD_ + lane];
    #pragma unroll
    for (int r = 0; r < 8; ++r)
      acc[r] = fmaf(x0[r * FD_ + f], wv, acc[r]);
  }
  unsigned short u[8];
  #pragma unroll
  for (int r = 0; r < 8; ++r) {
    unsigned x = __float_as_uint(acc[r]);
    u[r] = (unsigned short)((x + 0x7FFFu + ((x >> 16) & 1u)) >> 16);  // RNE
  }
  uint4 pk;
  pk.x = u[0] | ((unsigned)u[1] << 16);
  pk.y = u[2] | ((unsigned)u[3] << 16);
  pk.z = u[4] | ((unsigned)u[5] << 16);
  pk.w = u[6] | ((unsigned)u[7] << 16);
  *(uint4*)(Vt + ((size_t)bh * HD_ + lane) * N + (size_t)n8 * 8) = pk;
  const float a1v = a1[h * HD_ + lane], a2v = a2[h * HD_ + lane];
  #pragma unroll
  for (int r = 0; r < 8; ++r) {
    float d1 = wave_sum64(acc[r] * a1v);
    float d2 = wave_sum64(acc[r] * a2v);
    if (lane == 0) {
      dot1[(size_t)bh * N + n8 * 8 + r] = d1;
      dot2[(size_t)bh * N + n8 * 8 + r] = d2;
    }
  }
}

// ---- bitpack both adjacency matrices, grid-strided ----
__device__ __forceinline__ void bitpack_body(
    const int* __restrict__ adj_fe, const int* __restrict__ adj_ef,
    u64* __restrict__ bits_fe, u64* __restrict__ bits_ef, int sub)
{
  const int lane = threadIdx.x & 63;
  const int wid  = threadIdx.x >> 6;
  const int id = sub * 4 + wid;               // [0, 4096)
  const int WFE = NF_ * (NE_ / 64);           // 131072
  const int WTOT = WFE + NE_ * (NF_ / 64);    // 262144
  for (int w = id; w < WTOT; w += 4096) {
    int v;
    if (w < WFE) {
      const int n = w >> 6, mt = w & 63;
      v = adj_fe[(size_t)n * NE_ + mt * 64 + lane];
    } else {
      const int wm = w - WFE;
      const int n = wm >> 5, mt = wm & 31;
      v = adj_ef[(size_t)n * NF_ + mt * 64 + lane];
    }
    u64 mask = __ballot(v != 0);
    if (lane == 0) {
      if (w < WFE) bits_fe[w] = mask;
      else         bits_ef[w - WFE] = mask;
    }
  }
}

// ---- fused prep: proj_fe [0,512) | proj_ef [512,1536) | bitpack [1536,2560) ----
__global__ __launch_bounds__(256) void prep_kernel(
    const float* __restrict__ F0, const float* __restrict__ E0,
    const int* __restrict__ adj_fe, const int* __restrict__ adj_ef,
    const float* __restrict__ Wf, const float* __restrict__ We,
    const float* __restrict__ a_fe, const float* __restrict__ a_ef,
    __hip_bfloat16* __restrict__ Ft, __hip_bfloat16* __restrict__ Et,
    float* __restrict__ es_fe, float* __restrict__ ed_ef,
    float* __restrict__ ed_fe, float* __restrict__ es_ef,
    u64* __restrict__ bits_fe, u64* __restrict__ bits_ef)
{
  const int blk = blockIdx.x;
  const int wid = threadIdx.x >> 6;
  if (blk < 512) {
    proj_body(F0, Wf, a_fe, a_ef, Ft, es_fe, ed_ef, NF_, blk * 4 + wid);
  } else if (blk < 1536) {
    proj_body(E0, We, a_fe, a_ef, Et, ed_fe, es_ef, NE_, (blk - 512) * 4 + wid);
  } else {
    bitpack_body(adj_fe, adj_ef, bits_fe, bits_ef, blk - 1536);
  }
}

// ---- fused attention: block = 16 rows, 4 waves split M into quarters.
// LDS cross-wave reduction, direct final store (divided, relu for ef). ----
__global__ __launch_bounds__(256, 4) void attn_kernel(
    const __hip_bfloat16* __restrict__ Ft, const __hip_bfloat16* __restrict__ Et,
    const float* __restrict__ es_fe, const float* __restrict__ ed_fe,
    const float* __restrict__ es_ef, const float* __restrict__ ed_ef,
    const u64* __restrict__ bits_fe, const u64* __restrict__ bits_ef,
    float* __restrict__ out)
{
  __shared__ __align__(16) float ldsO[4 * 4 * 64 * 4];  // [db][src][lane][4] 16KB
  __shared__ float ldsS[4 * 16];

  const int lane = threadIdx.x & 63;
  const int wid  = threadIdx.x >> 6;
  const int cl = lane & 15, kq = lane >> 4;

  const int blk = blockIdx.x;
  int N, M, idx;
  const __hip_bfloat16* vp;
  const float *es, *ed;
  const u64* bits;
  float* obase;
  bool relu;
  if (blk < 1024) {
    idx = blk; N = NF_; M = NE_; vp = Et; es = es_fe; ed = ed_fe;
    bits = bits_fe; obase = out; relu = false;
  } else {
    idx = blk - 1024; N = NE_; M = NF_; vp = Ft; es = es_ef; ed = ed_ef;
    bits = bits_ef; obase = out + (size_t)B_ * NF_ * 256; relu = true;
  }
  const int nch = N >> 4;
  const int nc = idx % nch;
  const int bh = idx / nch;
  const int b = bh >> 2, h = bh & 3;
  const int n0 = nc * 16;
  const int MT = M >> 6;
  const int TQ = MT >> 2;        // tiles per wave (fe:16, ef:8)
  const int mt0 = wid * TQ;

  const float* esp = es + (size_t)bh * N;
  const float* edp = ed + (size_t)bh * M;
  const __hip_bfloat16* vpp = vp + (size_t)bh * HD_ * M;
  const u64* bp = bits + (size_t)(n0 + cl) * MT;
  const float esv = esp[n0 + cl];

  f32x4 accT[4] = {};
  f32x4 accS = {0.f, 0.f, 0.f, 0.f};
  bf16x8 ones;
  #pragma unroll
  for (int i = 0; i < 8; ++i) ones[i] = (short)0x3F80;  // bf16 1.0

  for (int t = 0; t < TQ; ++t) {
    const int mt = mt0 + t;
    const u64 mask = bp[mt];
    bf16x8 vf[2][4];
    #pragma unroll
    for (int ks = 0; ks < 2; ++ks)
      #pragma unroll
      for (int db = 0; db < 4; ++db)
        vf[ks][db] = *(const bf16x8*)(vpp + (size_t)(db * 16 + cl) * M
                                      + mt * 64 + ks * 32 + kq * 8);
    const float* e0 = edp + mt * 64 + kq * 8;
    const f32x4 ed0a = *(const f32x4*)(e0);
    const f32x4 ed0b = *(const f32x4*)(e0 + 4);
    const f32x4 ed1a = *(const f32x4*)(e0 + 32);
    const f32x4 ed1b = *(const f32x4*)(e0 + 36);

    bf16x8 pf[2];
    #pragma unroll
    for (int ks = 0; ks < 2; ++ks) {
      const unsigned mw = (unsigned)((mask >> (ks * 32 + kq * 8)) & 0xffull);
      #pragma unroll
      for (int j = 0; j < 8; ++j) {
        float edv = ks ? (j < 4 ? ed1a[j] : ed1b[j - 4])
                       : (j < 4 ? ed0a[j] : ed0b[j - 4]);
        float s = esv + edv;
        s = fmaxf(s, 0.2f * s);          // leaky_relu(0.2)
        float e = __expf(s - 12.0f);     // fixed max (|s| << 12)
        e = (mw & (1u << j)) ? e : 0.0f; // mask AFTER lrelu
        __hip_bfloat16 hb = __float2bfloat16(e);
        pf[ks][j] = *(short*)&hb;
      }
    }
    #pragma unroll
    for (int ks = 0; ks < 2; ++ks) {
      accS = __builtin_amdgcn_mfma_f32_16x16x32_bf16(pf[ks], ones, accS, 0, 0, 0);
      #pragma unroll
      for (int db = 0; db < 4; ++db)
        accT[db] = __builtin_amdgcn_mfma_f32_16x16x32_bf16(pf[ks], vf[ks][db],
                                                           accT[db], 0, 0, 0);
    }
  }

  // ---- cross-wave reduction in LDS (all-static indexing) ----
  #pragma unroll
  for (int db = 0; db < 4; ++db)
    *(f32x4*)&ldsO[((db * 4 + wid) * 64 + lane) * 4] = accT[db];
  if (cl == 0) {
    #pragma unroll
    for (int reg = 0; reg < 4; ++reg)
      ldsS[wid * 16 + kq * 4 + reg] = accS[reg];
  }
  __syncthreads();

  f32x4 osum = {0.f, 0.f, 0.f, 0.f};
  #pragma unroll
  for (int s = 0; s < 4; ++s)
    osum += *(const f32x4*)&ldsO[((wid * 4 + s) * 64 + lane) * 4];
  float stot[4];
  #pragma unroll
  for (int reg = 0; reg < 4; ++reg) {
    stot[reg] = 0.f;
    #pragma unroll
    for (int s = 0; s < 4; ++s) stot[reg] += ldsS[s * 16 + kq * 4 + reg];
  }
  // lane stores rows kq*4+reg, d = wid*16+cl
  float* orow = obase + ((size_t)b * N + n0 + kq * 4) * 256 + h * HD_ + wid * 16 + cl;
  #pragma unroll
  for (int reg = 0; reg < 4; ++reg) {
    float v = osum[reg] / stot[reg];
    if (relu) v = fmaxf(v, 0.0f);
    orow[reg * 256] = v;
  }
}

// in-place softmax over the 256-channel axis (one row per block)
__global__ __launch_bounds__(256) void softmax256_kernel(float* __restrict__ io)
{
  const int t = threadIdx.x;
  const int lane = t & 63, wid = t >> 6;
  float v = io[(long)blockIdx.x * 256 + t];
  __shared__ float red[8];
  float m = wave_max64(v);
  if (lane == 0) red[wid] = m;
  __syncthreads();
  m = fmaxf(fmaxf(red[0], red[1]), fmaxf(red[2], red[3]));
  float e = __expf(v - m);
  float s = wave_sum64(e);
  if (lane == 0) red[4 + wid] = s;
  __syncthreads();
  s = (red[4] + red[5]) + (red[6] + red[7]);
  io[(long)blockIdx.x * 256 + t] = e / s;
}

extern "C" void kernel_launch(void* const* d_in, const int* in_sizes, int n_in,
                              void* d_out, int out_size, void* d_ws, size_t ws_size,
                              hipStream_t stream)
{
  const float* F0   = (const float*)d_in[0];
  const float* E0   = (const float*)d_in[1];
  const int* adj_fe = (const int*)d_in[2];
  const int* adj_ef = (const int*)d_in[3];
  const float* Wf   = (const float*)d_in[4];
  const float* We   = (const float*)d_in[5];
  const float* a_fe = (const float*)d_in[6];
  const float* a_ef = (const float*)d_in[7];
  float* out = (float*)d_out;

  float* ws = (float*)d_ws;
  float* es_fe = ws;                               // 8*2048
  float* ed_ef = es_fe + (size_t)B_ * H_ * NF_;    // 8*2048
  float* ed_fe = ed_ef + (size_t)B_ * H_ * NF_;    // 8*4096
  float* es_ef = ed_fe + (size_t)B_ * H_ * NE_;    // 8*4096
  u64* bits_fe = (u64*)(es_ef + (size_t)B_ * H_ * NE_);   // 2048*64 u64
  u64* bits_ef = bits_fe + (size_t)NF_ * (NE_ / 64);      // 4096*32 u64
  __hip_bfloat16* Ft = (__hip_bfloat16*)(bits_ef + (size_t)NE_ * (NF_ / 64));
  __hip_bfloat16* Et = Ft + (size_t)B_ * H_ * HD_ * NF_;

  prep_kernel<<<2560, 256, 0, stream>>>(F0, E0, adj_fe, adj_ef, Wf, We,
                                        a_fe, a_ef, Ft, Et,
                                        es_fe, ed_ef, ed_fe, es_ef,
                                        bits_fe, bits_ef);
  attn_kernel<<<3072, 256, 0, stream>>>(Ft, Et, es_fe, ed_fe, es_ef, ed_ef,
                                        bits_fe, bits_ef, out);
  softmax256_kernel<<<B_ * NF_, 256, 0, stream>>>(out);
}

// Round 5
// 200.828 us; speedup vs baseline: 4.8713x; 1.1292x over previous
//
#include <hip/hip_runtime.h>
#include <hip/hip_bf16.h>
#include <stdint.h>

#define B_  2
#define NF_ 2048
#define NE_ 4096
#define FD_ 128
#define HD_ 64
#define H_  4

#define LOG2E 1.44269504f
#define C2    17.3123405f   // 12 * log2e

typedef unsigned long long u64;
typedef __attribute__((ext_vector_type(4))) float f32x4;
typedef __attribute__((ext_vector_type(8))) short bf16x8;

__device__ __forceinline__ float wave_sum64(float v) {
  #pragma unroll
  for (int m = 32; m >= 1; m >>= 1) v += __shfl_xor(v, m, 64);
  return v;
}
__device__ __forceinline__ float wave_max64(float v) {
  #pragma unroll
  for (int m = 32; m >= 1; m >>= 1) v = fmaxf(v, __shfl_xor(v, m, 64));
  return v;
}

// ---- proj: 8 rows/wave; writes transposed bf16 Vt[bh][d][n] + log2e-scaled dots ----
__device__ __forceinline__ void proj_body(
    const float* __restrict__ X0, const float* __restrict__ W,
    const float* __restrict__ a1, const float* __restrict__ a2,
    __hip_bfloat16* __restrict__ Vt, float* __restrict__ dot1,
    float* __restrict__ dot2, int N, int job)
{
  const int lane = threadIdx.x & 63;
  const int nj = N >> 3;
  const int n8 = job % nj;
  const int h  = (job / nj) & (H_ - 1);
  const int b  = job / (nj * H_);
  const int bh = b * H_ + h;
  const float* x0 = X0 + ((size_t)b * N + (size_t)n8 * 8) * FD_;
  const float* w  = W + (size_t)h * FD_ * HD_;
  float acc[8] = {0,0,0,0,0,0,0,0};
  #pragma unroll 4
  for (int f = 0; f < FD_; ++f) {
    float wv = w[f * HD_ + lane];
    #pragma unroll
    for (int r = 0; r < 8; ++r)
      acc[r] = fmaf(x0[r * FD_ + f], wv, acc[r]);
  }
  unsigned short u[8];
  #pragma unroll
  for (int r = 0; r < 8; ++r) {
    unsigned x = __float_as_uint(acc[r]);
    u[r] = (unsigned short)((x + 0x7FFFu + ((x >> 16) & 1u)) >> 16);  // RNE
  }
  uint4 pk;
  pk.x = u[0] | ((unsigned)u[1] << 16);
  pk.y = u[2] | ((unsigned)u[3] << 16);
  pk.z = u[4] | ((unsigned)u[5] << 16);
  pk.w = u[6] | ((unsigned)u[7] << 16);
  *(uint4*)(Vt + ((size_t)bh * HD_ + lane) * N + (size_t)n8 * 8) = pk;
  const float a1v = a1[h * HD_ + lane] * LOG2E;   // pre-scale for exp2
  const float a2v = a2[h * HD_ + lane] * LOG2E;
  #pragma unroll
  for (int r = 0; r < 8; ++r) {
    float d1 = wave_sum64(acc[r] * a1v);
    float d2 = wave_sum64(acc[r] * a2v);
    if (lane == 0) {
      dot1[(size_t)bh * N + n8 * 8 + r] = d1;
      dot2[(size_t)bh * N + n8 * 8 + r] = d2;
    }
  }
}

// ---- bitpack, TRANSPOSED output bits_t[mt][n]; 16-row jobs, coalesced ----
__device__ __forceinline__ void bitpack_body(
    const int* __restrict__ adj_fe, const int* __restrict__ adj_ef,
    u64* __restrict__ btfe, u64* __restrict__ btef, int sub)
{
  const int lane = threadIdx.x & 63;
  const int wid  = threadIdx.x >> 6;
  const int base = sub * 4 + wid;               // [0, 4096)
  #pragma unroll
  for (int rep = 0; rep < 4; ++rep) {
    const int id = base + rep * 4096;           // [0, 16384)
    const int* adj; u64* bt; int N, M, mt, g;
    if (id < 8192) {                            // fe: 64 mt x 128 g
      adj = adj_fe; bt = btfe; N = NF_; M = NE_;
      mt = id >> 7; g = id & 127;
    } else {                                    // ef: 32 mt x 256 g
      const int k = id - 8192;
      adj = adj_ef; bt = btef; N = NE_; M = NF_;
      mt = k >> 8; g = k & 255;
    }
    u64 mine = 0;
    #pragma unroll
    for (int r = 0; r < 16; ++r) {
      int v = adj[(size_t)(g * 16 + r) * M + mt * 64 + lane];
      u64 msk = __ballot(v != 0);
      if (lane == r) mine = msk;
    }
    if (lane < 16) bt[(size_t)mt * N + g * 16 + lane] = mine;
  }
}

// ---- fused prep: proj_fe [0,512) | proj_ef [512,1536) | bitpack [1536,2560) ----
__global__ __launch_bounds__(256) void prep_kernel(
    const float* __restrict__ F0, const float* __restrict__ E0,
    const int* __restrict__ adj_fe, const int* __restrict__ adj_ef,
    const float* __restrict__ Wf, const float* __restrict__ We,
    const float* __restrict__ a_fe, const float* __restrict__ a_ef,
    __hip_bfloat16* __restrict__ Ft, __hip_bfloat16* __restrict__ Et,
    float* __restrict__ es_fe, float* __restrict__ ed_ef,
    float* __restrict__ ed_fe, float* __restrict__ es_ef,
    u64* __restrict__ btfe, u64* __restrict__ btef)
{
  const int blk = blockIdx.x;
  const int wid = threadIdx.x >> 6;
  if (blk < 512) {
    proj_body(F0, Wf, a_fe, a_ef, Ft, es_fe, ed_ef, NF_, blk * 4 + wid);
  } else if (blk < 1536) {
    proj_body(E0, We, a_fe, a_ef, Et, ed_fe, es_ef, NE_, (blk - 512) * 4 + wid);
  } else {
    bitpack_body(adj_fe, adj_ef, btfe, btef, blk - 1536);
  }
}

// ---- per-wave attention inner loop, TQ tiles, ed/mask prefetched 1 ahead ----
template<int TQ>
__device__ __forceinline__ void attn_wave(
    const __hip_bfloat16* __restrict__ vpp, const float* __restrict__ edp,
    const u64* __restrict__ bt, float esv, int M, int N, int n0, int mt0,
    int cl, int kq, f32x4 (&accT)[4], f32x4 &accS)
{
  bf16x8 ones;
  #pragma unroll
  for (int i = 0; i < 8; ++i) ones[i] = (short)0x3F80;  // bf16 1.0

  f32x4 edA[4], edB[4];
  u64 mA, mB;

  auto load_ed = [&](int mt, f32x4 (&er)[4], u64 &mk) {
    const float* e0 = edp + mt * 64 + kq * 8;
    er[0] = *(const f32x4*)(e0);
    er[1] = *(const f32x4*)(e0 + 4);
    er[2] = *(const f32x4*)(e0 + 32);
    er[3] = *(const f32x4*)(e0 + 36);
    mk = bt[(size_t)mt * N + n0 + cl];
  };

  auto comp = [&](int mt, const f32x4 (&er)[4], u64 mk) {
    #pragma unroll
    for (int ks = 0; ks < 2; ++ks) {
      bf16x8 vf[4];
      #pragma unroll
      for (int db = 0; db < 4; ++db)       // issue early; consumed after P-VALU
        vf[db] = *(const bf16x8*)(vpp + (size_t)(db * 16 + cl) * M
                                  + mt * 64 + ks * 32 + kq * 8);
      const unsigned mw = (unsigned)(mk >> (ks * 32 + kq * 8)) & 0xffu;
      bf16x8 pf;
      #pragma unroll
      for (int j = 0; j < 8; ++j) {
        float s = esv + er[ks * 2 + (j >> 2)][j & 3];
        s = fmaxf(s, 0.2f * s);            // leaky_relu (scale-invariant)
        float e = exp2f(s - C2);           // == exp(s_unscaled - 12)
        e = (mw & (1u << j)) ? e : 0.0f;   // mask AFTER lrelu
        __hip_bfloat16 hb = __float2bfloat16(e);
        pf[j] = *(short*)&hb;
      }
      accS = __builtin_amdgcn_mfma_f32_16x16x32_bf16(pf, ones, accS, 0, 0, 0);
      #pragma unroll
      for (int db = 0; db < 4; ++db)
        accT[db] = __builtin_amdgcn_mfma_f32_16x16x32_bf16(pf, vf[db],
                                                           accT[db], 0, 0, 0);
    }
  };

  load_ed(mt0, edA, mA);
  #pragma unroll 1
  for (int t = 0; t < TQ; t += 2) {
    load_ed(mt0 + t + 1, edB, mB);
    comp(mt0 + t, edA, mA);
    if (t + 2 < TQ) load_ed(mt0 + t + 2, edA, mA);
    comp(mt0 + t + 1, edB, mB);
  }
}

// ---- fused attention: block = 16 rows, 4 waves split M; XCD-local bh ----
__global__ __launch_bounds__(256, 4) void attn_kernel(
    const __hip_bfloat16* __restrict__ Ft, const __hip_bfloat16* __restrict__ Et,
    const float* __restrict__ es_fe, const float* __restrict__ ed_fe,
    const float* __restrict__ es_ef, const float* __restrict__ ed_ef,
    const u64* __restrict__ btfe, const u64* __restrict__ btef,
    float* __restrict__ out)
{
  __shared__ __align__(16) float ldsO[4 * 4 * 64 * 4];  // [db][src][lane][4] 16KB
  __shared__ float ldsS[4 * 16];

  const int lane = threadIdx.x & 63;
  const int wid  = threadIdx.x >> 6;
  const int cl = lane & 15, kq = lane >> 4;
  const int blk = blockIdx.x;

  int N, bh, n0;
  float* obase;
  bool relu;
  f32x4 accT[4] = {};
  f32x4 accS = {0.f, 0.f, 0.f, 0.f};

  if (blk < 1024) {            // fe: bh = blk & 7 -> one bh per XCD
    bh = blk & 7;
    n0 = (blk >> 3) * 16;
    N = NF_;
    const float esv = es_fe[(size_t)bh * NF_ + n0 + cl];
    attn_wave<16>(Et + (size_t)bh * HD_ * NE_, ed_fe + (size_t)bh * NE_,
                  btfe, esv, NE_, NF_, n0, wid * 16, cl, kq, accT, accS);
    obase = out; relu = false;
  } else {                     // ef
    const int k2 = blk - 1024;
    bh = k2 & 7;
    n0 = (k2 >> 3) * 16;
    N = NE_;
    const float esv = es_ef[(size_t)bh * NE_ + n0 + cl];
    attn_wave<8>(Ft + (size_t)bh * HD_ * NF_, ed_ef + (size_t)bh * NF_,
                 btef, esv, NF_, NE_, n0, wid * 8, cl, kq, accT, accS);
    obase = out + (size_t)B_ * NF_ * 256; relu = true;
  }

  // ---- cross-wave reduction in LDS (all-static indexing) ----
  #pragma unroll
  for (int db = 0; db < 4; ++db)
    *(f32x4*)&ldsO[((db * 4 + wid) * 64 + lane) * 4] = accT[db];
  if (cl == 0) {
    #pragma unroll
    for (int reg = 0; reg < 4; ++reg)
      ldsS[wid * 16 + kq * 4 + reg] = accS[reg];
  }
  __syncthreads();

  f32x4 osum = {0.f, 0.f, 0.f, 0.f};
  #pragma unroll
  for (int s = 0; s < 4; ++s)
    osum += *(const f32x4*)&ldsO[((wid * 4 + s) * 64 + lane) * 4];
  float stot[4];
  #pragma unroll
  for (int reg = 0; reg < 4; ++reg) {
    stot[reg] = 0.f;
    #pragma unroll
    for (int s = 0; s < 4; ++s) stot[reg] += ldsS[s * 16 + kq * 4 + reg];
  }
  const int b = bh >> 2, h = bh & 3;
  float* orow = obase + ((size_t)b * N + n0 + kq * 4) * 256 + h * HD_ + wid * 16 + cl;
  #pragma unroll
  for (int reg = 0; reg < 4; ++reg) {
    float v = osum[reg] / stot[reg];
    if (relu) v = fmaxf(v, 0.0f);
    orow[reg * 256] = v;
  }
}

// in-place softmax over the 256-channel axis (one row per block)
__global__ __launch_bounds__(256) void softmax256_kernel(float* __restrict__ io)
{
  const int t = threadIdx.x;
  const int lane = t & 63, wid = t >> 6;
  float v = io[(long)blockIdx.x * 256 + t];
  __shared__ float red[8];
  float m = wave_max64(v);
  if (lane == 0) red[wid] = m;
  __syncthreads();
  m = fmaxf(fmaxf(red[0], red[1]), fmaxf(red[2], red[3]));
  float e = __expf(v - m);
  float s = wave_sum64(e);
  if (lane == 0) red[4 + wid] = s;
  __syncthreads();
  s = (red[4] + red[5]) + (red[6] + red[7]);
  io[(long)blockIdx.x * 256 + t] = e / s;
}

extern "C" void kernel_launch(void* const* d_in, const int* in_sizes, int n_in,
                              void* d_out, int out_size, void* d_ws, size_t ws_size,
                              hipStream_t stream)
{
  const float* F0   = (const float*)d_in[0];
  const float* E0   = (const float*)d_in[1];
  const int* adj_fe = (const int*)d_in[2];
  const int* adj_ef = (const int*)d_in[3];
  const float* Wf   = (const float*)d_in[4];
  const float* We   = (const float*)d_in[5];
  const float* a_fe = (const float*)d_in[6];
  const float* a_ef = (const float*)d_in[7];
  float* out = (float*)d_out;

  float* ws = (float*)d_ws;
  float* es_fe = ws;                               // 8*2048
  float* ed_ef = es_fe + (size_t)B_ * H_ * NF_;    // 8*2048
  float* ed_fe = ed_ef + (size_t)B_ * H_ * NF_;    // 8*4096
  float* es_ef = ed_fe + (size_t)B_ * H_ * NE_;    // 8*4096
  u64* btfe = (u64*)(es_ef + (size_t)B_ * H_ * NE_);   // [64][2048] u64
  u64* btef = btfe + (size_t)(NE_ / 64) * NF_;         // [32][4096] u64
  __hip_bfloat16* Ft = (__hip_bfloat16*)(btef + (size_t)(NF_ / 64) * NE_);
  __hip_bfloat16* Et = Ft + (size_t)B_ * H_ * HD_ * NF_;

  prep_kernel<<<2560, 256, 0, stream>>>(F0, E0, adj_fe, adj_ef, Wf, We,
                                        a_fe, a_ef, Ft, Et,
                                        es_fe, ed_ef, ed_fe, es_ef,
                                        btfe, btef);
  attn_kernel<<<3072, 256, 0, stream>>>(Ft, Et, es_fe, ed_fe, es_ef, ed_ef,
                                        btfe, btef, out);
  softmax256_kernel<<<B_ * NF_, 256, 0, stream>>>(out);
}